// Round 8
// baseline (132.400 us; speedup 1.0000x reference)
//
#include <hip/hip_runtime.h>
#include <hip/hip_bf16.h>

// SemanticDecoder: mean = b@Wmu+bmu; s = b@Wsig+bsig; var = s*s;
// sample = mean + |s|*eps.  B=65536, K=64, D=300. f32 in/out.
// Outputs concatenated: [sample, mean, var], each B*D.
//
// R8: two-kernel split. R7's asm-pin falsified the weight-remat theory
// (pinned weights, same 128us) -> fused dot2 family is latency/payload-bound.
// k1 = R4's verified MFMA GEMM, but storing ONLY mean(f32)->out_mean and
// s(f32)->out_var (placeholder). No eps gathers, no 3-stream scatter.
// k2 = pure linear float4 streaming (300=75*4 -> quad index is linear over
// B*D): sample = mean + |s|*eps, var = s*s. fillBuffer-class pattern.

#define B_ROWS 65536
#define K_DIM 64
#define D_DIM 300
#define NFRAG 19          // ceil(300/16); frag 18 cols 288..303 masked
#define HALF0_NF 10
#define LDS_FRAGS 10
#define GEMM_THREADS 512
#define GEMM_ROWS 128

typedef __fp16 half2v __attribute__((ext_vector_type(2)));
typedef __fp16 half8v __attribute__((ext_vector_type(8)));
typedef float  f32x4  __attribute__((ext_vector_type(4)));

__device__ __forceinline__ half8v pack8(float4 x, float4 y) {
    half2v p0 = __builtin_amdgcn_cvt_pkrtz(x.x, x.y);
    half2v p1 = __builtin_amdgcn_cvt_pkrtz(x.z, x.w);
    half2v p2 = __builtin_amdgcn_cvt_pkrtz(y.x, y.y);
    half2v p3 = __builtin_amdgcn_cvt_pkrtz(y.z, y.w);
    half8v r;
    r[0] = p0[0]; r[1] = p0[1]; r[2] = p1[0]; r[3] = p1[1];
    r[4] = p2[0]; r[5] = p2[1]; r[6] = p3[0]; r[7] = p3[1];
    return r;
}

// ---- kernel 0: pack W[64][300] f32 -> f16 MFMA B-fragments (d_ws) --------
// unit t = ((m*NFRAG + f)*2 + s)*64 + lane ; holds 8 f16:
//   W_m[k = s*32 + (lane>>4)*8 + e][col = f*16 + (lane&15)], e = 0..7
__global__ void pack_w_kernel(const float* __restrict__ Wmu,
                              const float* __restrict__ Wsig,
                              half8v* __restrict__ wpack)
{
    const int t = blockIdx.x * blockDim.x + threadIdx.x;
    const int total = 2 * NFRAG * 2 * 64;  // 4864
    if (t >= total) return;
    const int lane = t & 63;
    const int fs   = t >> 6;
    const int s    = fs & 1;
    const int mf   = fs >> 1;
    const int m    = mf / NFRAG;
    const int f    = mf - m * NFRAG;
    const int col  = f * 16 + (lane & 15);
    const int k0   = s * 32 + (lane >> 4) * 8;
    const float* W = m ? Wsig : Wmu;
    half8v o;
    #pragma unroll
    for (int e = 0; e < 8; ++e) {
        float v = (col < D_DIM) ? W[(size_t)(k0 + e) * D_DIM + col] : 0.f;
        o[e] = (__fp16)v;
    }
    wpack[t] = o;
}

// ---- kernel 1: GEMM -> mean (out+BD), s (out+2BD, placeholder) -----------
__global__ __launch_bounds__(GEMM_THREADS, 4) void sem_dec_gemm(
    const float* __restrict__ b,
    const float* __restrict__ bmu,
    const float* __restrict__ bsig,
    const half8v* __restrict__ wpack,
    float* __restrict__ out)
{
    __shared__ half8v wlds[2 * LDS_FRAGS * 2 * 64];  // 40960 B

    const int tid     = threadIdx.x;
    const int lane    = tid & 63;
    const int wid     = tid >> 6;             // 0..7, one 16-row tile per wave
    const int half_id = blockIdx.y;           // 0: frags 0-9, 1: frags 10-18
    const int f0      = half_id * HALF0_NF;
    const int nf      = half_id ? (NFRAG - HALF0_NF) : HALF0_NF;
    const int rowbase = blockIdx.x * GEMM_ROWS + wid * 16;

    // A fragments: row = lane&15, k = (lane>>4)*8 + e (+32 for slice 1)
    const int arow = lane & 15;
    const int kg   = lane >> 4;
    const float* bp = b + (size_t)(rowbase + arow) * K_DIM + kg * 8;
    float4 v0 = *reinterpret_cast<const float4*>(bp);
    float4 v1 = *reinterpret_cast<const float4*>(bp + 4);
    float4 v2 = *reinterpret_cast<const float4*>(bp + 32);
    float4 v3 = *reinterpret_cast<const float4*>(bp + 36);
    half8v a0 = pack8(v0, v1);
    half8v a1 = pack8(v2, v3);

    // stage this half's packed weights -> LDS
    {
        const int n = nf * 2 * 64;
        #pragma unroll
        for (int m = 0; m < 2; ++m) {
            const half8v* src = wpack + (m * NFRAG + f0) * 2 * 64;
            half8v* dst = wlds + m * (LDS_FRAGS * 2 * 64);
            for (int i = tid; i < n; i += GEMM_THREADS)
                dst[i] = src[i];
        }
    }
    __syncthreads();

    const size_t BD = (size_t)B_ROWS * D_DIM;
    const int ccol = lane & 15;
    const int crow = (lane >> 4) * 4;         // + reg 0..3 (m89-verified C map)

    #pragma unroll
    for (int fi = 0; fi < LDS_FRAGS; ++fi) {
        const int c = (f0 + fi) * 16 + ccol;
        const bool cval = (c < D_DIM);
        half8v wm0 = wlds[((0 * LDS_FRAGS + fi) * 2 + 0) * 64 + lane];
        half8v wm1 = wlds[((0 * LDS_FRAGS + fi) * 2 + 1) * 64 + lane];
        half8v ws0 = wlds[((1 * LDS_FRAGS + fi) * 2 + 0) * 64 + lane];
        half8v ws1 = wlds[((1 * LDS_FRAGS + fi) * 2 + 1) * 64 + lane];
        const float biasm = cval ? bmu[c] : 0.f;
        const float biass = cval ? bsig[c] : 0.f;
        f32x4 accm = {biasm, biasm, biasm, biasm};
        f32x4 accs = {biass, biass, biass, biass};
        accm = __builtin_amdgcn_mfma_f32_16x16x32_f16(a0, wm0, accm, 0, 0, 0);
        accm = __builtin_amdgcn_mfma_f32_16x16x32_f16(a1, wm1, accm, 0, 0, 0);
        accs = __builtin_amdgcn_mfma_f32_16x16x32_f16(a0, ws0, accs, 0, 0, 0);
        accs = __builtin_amdgcn_mfma_f32_16x16x32_f16(a1, ws1, accs, 0, 0, 0);
        if (cval) {
            #pragma unroll
            for (int r = 0; r < 4; ++r) {
                const size_t o = (size_t)(rowbase + crow + r) * D_DIM + c;
                out[o + BD]     = accm[r];   // mean (final)
                out[o + 2 * BD] = accs[r];   // s (placeholder, k2 -> s*s)
            }
        }
    }
}

// ---- kernel 2: streaming epilogue ---------------------------------------
// 300 = 75*4 -> float4-quad index is LINEAR over the whole B*D array.
// Each thread handles 2 adjacent quads (32B per stream) per iteration.
__global__ __launch_bounds__(256) void sem_dec_finish(
    const float* __restrict__ eps,
    float* __restrict__ out)
{
    const size_t BD = (size_t)B_ROWS * D_DIM;
    const size_t NP = BD / 8;                 // 2,457,600 quad-pairs
    const float4* eps4  = reinterpret_cast<const float4*>(eps);
    const float4* mean4 = reinterpret_cast<const float4*>(out + BD);
    float4* var4  = reinterpret_cast<float4*>(out + 2 * BD);
    float4* samp4 = reinterpret_cast<float4*>(out);

    const size_t stride = (size_t)gridDim.x * blockDim.x;
    for (size_t p = (size_t)blockIdx.x * blockDim.x + threadIdx.x;
         p < NP; p += stride) {
        const size_t i0 = 2 * p, i1 = 2 * p + 1;
        // issue all 6 loads before use
        float4 m0 = mean4[i0], m1 = mean4[i1];
        float4 s0 = var4[i0],  s1 = var4[i1];   // holds s from k1
        float4 e0 = eps4[i0],  e1 = eps4[i1];
        float4 o0, o1, w0, w1;
        o0.x = fmaf(fabsf(s0.x), e0.x, m0.x);  w0.x = s0.x * s0.x;
        o0.y = fmaf(fabsf(s0.y), e0.y, m0.y);  w0.y = s0.y * s0.y;
        o0.z = fmaf(fabsf(s0.z), e0.z, m0.z);  w0.z = s0.z * s0.z;
        o0.w = fmaf(fabsf(s0.w), e0.w, m0.w);  w0.w = s0.w * s0.w;
        o1.x = fmaf(fabsf(s1.x), e1.x, m1.x);  w1.x = s1.x * s1.x;
        o1.y = fmaf(fabsf(s1.y), e1.y, m1.y);  w1.y = s1.y * s1.y;
        o1.z = fmaf(fabsf(s1.z), e1.z, m1.z);  w1.z = s1.z * s1.z;
        o1.w = fmaf(fabsf(s1.w), e1.w, m1.w);  w1.w = s1.w * s1.w;
        samp4[i0] = o0;
        samp4[i1] = o1;
        var4[i0]  = w0;
        var4[i1]  = w1;
    }
}

extern "C" void kernel_launch(void* const* d_in, const int* in_sizes, int n_in,
                              void* d_out, int out_size, void* d_ws, size_t ws_size,
                              hipStream_t stream) {
    const float* b    = (const float*)d_in[0];
    // d_in[1] = labels (unused by the reference outputs)
    const float* Wmu  = (const float*)d_in[2];
    const float* bmu  = (const float*)d_in[3];
    const float* Wsig = (const float*)d_in[4];
    const float* bsig = (const float*)d_in[5];
    const float* eps  = (const float*)d_in[6];
    float* out = (float*)d_out;
    half8v* wpack = (half8v*)d_ws;            // 4864 * 16 B = 77824 B

    hipLaunchKernelGGL(pack_w_kernel, dim3(19), dim3(256), 0, stream,
                       Wmu, Wsig, wpack);
    hipLaunchKernelGGL(sem_dec_gemm, dim3(B_ROWS / GEMM_ROWS, 2),
                       dim3(GEMM_THREADS), 0, stream,
                       b, bmu, bsig, wpack, out);
    hipLaunchKernelGGL(sem_dec_finish, dim3(2048), dim3(256), 0, stream,
                       eps, out);
}

// Round 9
// 121.225 us; speedup vs baseline: 1.0922x; 1.0922x over previous
//
#include <hip/hip_runtime.h>
#include <hip/hip_bf16.h>

// SemanticDecoder: mean = b@Wmu+bmu; s = b@Wsig+bsig; var = s*s;
// sample = mean + |s|*eps.  B=65536, K=64, D=300. f32 in/out.
// Outputs concatenated: [sample, mean, var], each B*D.
//
// R9: NO LDS. Theory: all fused variants were bound by the per-CU LDS pipe
// (8x ds_read_b128 broadcast per row per wave ~= 51us/CU serialized; R1's
// f32 16-read variant = ~102us, matching its 172 vs 127). The b-row address
// is wave-uniform in thread-per-column layout -> load b directly from
// global (uniform load = 1 L1 transaction broadcast, VMEM pipe ~1cy/instr).
// No staging, no syncthreads. Weights f16 in VGPRs, asm-pinned (R7-proven).
// If ws_size allows, pre-pack b to f16 (4 uniform loads/row, no cvt).

#define B_ROWS 65536
#define K_DIM 64
#define D_DIM 300
#define ROWS_PER_BLOCK 64
#define THREADS 320   // 5 waves; threads 0..299 own one output column

typedef __fp16 half2v __attribute__((ext_vector_type(2)));
typedef __fp16 half8v __attribute__((ext_vector_type(8)));

__device__ __forceinline__ float dot2h(half2v a, half2v b, float c) {
#if __has_builtin(__builtin_amdgcn_fdot2)
    return __builtin_amdgcn_fdot2(a, b, c, false);
#else
    return fmaf((float)a[0], (float)b[0], fmaf((float)a[1], (float)b[1], c));
#endif
}

__device__ __forceinline__ half2v h2(unsigned int u) {
    return __builtin_bit_cast(half2v, u);
}
__device__ __forceinline__ unsigned int pkd(float a, float b) {
    return __builtin_bit_cast(unsigned int, __builtin_amdgcn_cvt_pkrtz(a, b));
}

// ---- optional kernel: pack b[65536][64] f32 -> f16 in d_ws ----------------
__global__ __launch_bounds__(256) void pack_b_kernel(
    const float* __restrict__ b, __fp16* __restrict__ bh)
{
    const size_t N8 = (size_t)B_ROWS * K_DIM / 8;   // 524288 units of 8
    const size_t i = (size_t)blockIdx.x * blockDim.x + threadIdx.x;
    if (i >= N8) return;
    const float4* s = reinterpret_cast<const float4*>(b) + 2 * i;
    const float4 x = s[0], y = s[1];
    uint4 o;
    o.x = pkd(x.x, x.y);
    o.y = pkd(x.z, x.w);
    o.z = pkd(y.x, y.y);
    o.w = pkd(y.z, y.w);
    reinterpret_cast<uint4*>(bh)[i] = o;
}

// ---- main kernel (PACKED=1: b from f16 d_ws; 0: f32 b, cvt in-loop) ------
template<int PACKED>
__global__ __launch_bounds__(THREADS, 2) void sem_dec_kernel(
    const float* __restrict__ b,
    const __fp16* __restrict__ bh,
    const float* __restrict__ Wmu,
    const float* __restrict__ bmu,
    const float* __restrict__ Wsig,
    const float* __restrict__ bsig,
    const float* __restrict__ eps,
    float* __restrict__ out)
{
    const int tid  = threadIdx.x;
    const int row0 = blockIdx.x * ROWS_PER_BLOCK;
    const bool cval = (tid < D_DIM);
    const int d = cval ? tid : (D_DIM - 1);

    // ---- weight columns -> 64 packed-f16 dwords, pinned in VGPRs ----
    unsigned int wmd[32], wsd[32];
    #pragma unroll
    for (int k2 = 0; k2 < 32; ++k2) {
        wmd[k2] = pkd(Wmu[(size_t)(2 * k2) * D_DIM + d],
                      Wmu[(size_t)(2 * k2 + 1) * D_DIM + d]);
        wsd[k2] = pkd(Wsig[(size_t)(2 * k2) * D_DIM + d],
                      Wsig[(size_t)(2 * k2 + 1) * D_DIM + d]);
    }
    float bm = bmu[d];
    float bs = bsig[d];
    #pragma unroll
    for (int i = 0; i < 32; ++i) {
        asm volatile("" : "+v"(wmd[i]));   // opaque: no sinking/remat
        asm volatile("" : "+v"(wsd[i]));
    }
    asm volatile("" : "+v"(bm));
    asm volatile("" : "+v"(bs));

    const size_t BD = (size_t)B_ROWS * D_DIM;
    size_t o = (size_t)row0 * D_DIM + d;

    // eps pipeline: 2 rows of lead
    float e0 = eps[o];
    float e1 = eps[o + D_DIM];

    for (int r = 0; r < ROWS_PER_BLOCK; ++r) {
        // ---- b-row: WAVE-UNIFORM global loads (L1 broadcast, no LDS) ----
        uint4 q[8];
        if (PACKED) {
            const uint4* bq = reinterpret_cast<const uint4*>(
                bh + (size_t)(row0 + r) * K_DIM);
            #pragma unroll
            for (int j = 0; j < 8; ++j) q[j] = bq[j];
        } else {
            const float4* bf = reinterpret_cast<const float4*>(
                b + (size_t)(row0 + r) * K_DIM);
            #pragma unroll
            for (int j = 0; j < 8; ++j) {
                const float4 x = bf[2 * j], y = bf[2 * j + 1];
                q[j].x = pkd(x.x, x.y);
                q[j].y = pkd(x.z, x.w);
                q[j].z = pkd(y.x, y.y);
                q[j].w = pkd(y.z, y.w);
            }
        }
        // ---- 64 dot2, 4 independent chains ----
        float am0 = 0.f, am1 = 0.f, as0 = 0.f, as1 = 0.f;
        #pragma unroll
        for (int kk = 0; kk < 8; ++kk) {
            const half2v q0 = h2(q[kk].x), q1 = h2(q[kk].y);
            const half2v q2 = h2(q[kk].z), q3 = h2(q[kk].w);
            am0 = dot2h(q0, h2(wmd[4*kk+0]), am0);
            am1 = dot2h(q1, h2(wmd[4*kk+1]), am1);
            as0 = dot2h(q0, h2(wsd[4*kk+0]), as0);
            as1 = dot2h(q1, h2(wsd[4*kk+1]), as1);
            am0 = dot2h(q2, h2(wmd[4*kk+2]), am0);
            am1 = dot2h(q3, h2(wmd[4*kk+3]), am1);
            as0 = dot2h(q2, h2(wsd[4*kk+2]), as0);
            as1 = dot2h(q3, h2(wsd[4*kk+3]), as1);
        }
        const float ecur = e0;
        e0 = e1;
        if (r + 2 < ROWS_PER_BLOCK) e1 = eps[o + 2 * (size_t)D_DIM];

        const float mean = am0 + am1 + bm;
        const float s    = as0 + as1 + bs;
        if (cval) {
            out[o]          = fmaf(fabsf(s), ecur, mean);  // sample
            out[o + BD]     = mean;
            out[o + 2 * BD] = s * s;                       // var
        }
        o += D_DIM;
    }
}

extern "C" void kernel_launch(void* const* d_in, const int* in_sizes, int n_in,
                              void* d_out, int out_size, void* d_ws, size_t ws_size,
                              hipStream_t stream) {
    const float* b    = (const float*)d_in[0];
    // d_in[1] = labels (unused by the reference outputs)
    const float* Wmu  = (const float*)d_in[2];
    const float* bmu  = (const float*)d_in[3];
    const float* Wsig = (const float*)d_in[4];
    const float* bsig = (const float*)d_in[5];
    const float* eps  = (const float*)d_in[6];
    float* out = (float*)d_out;

    const size_t BH_BYTES = (size_t)B_ROWS * K_DIM * sizeof(__fp16); // 8 MB
    if (ws_size >= BH_BYTES) {
        __fp16* bhw = (__fp16*)d_ws;
        hipLaunchKernelGGL(pack_b_kernel, dim3(2048), dim3(256), 0, stream,
                           b, bhw);
        hipLaunchKernelGGL((sem_dec_kernel<1>), dim3(B_ROWS / ROWS_PER_BLOCK),
                           dim3(THREADS), 0, stream,
                           b, bhw, Wmu, bmu, Wsig, bsig, eps, out);
    } else {
        hipLaunchKernelGGL((sem_dec_kernel<0>), dim3(B_ROWS / ROWS_PER_BLOCK),
                           dim3(THREADS), 0, stream,
                           b, (const __fp16*)nullptr, Wmu, bmu, Wsig, bsig,
                           eps, out);
    }
}